// Round 12
// baseline (391.788 us; speedup 1.0000x reference)
//
#include <hip/hip_runtime.h>
#include <hip/hip_bf16.h>

#define N_NODES 50000
#define N_EDGES 600000
#define F 128

#define GEMM_BLOCKS 782   // ceil(50000/64)
#define NBINS 196         // ceil(50000/256), bin = dst >> 8
#define NHB 64            // histogram/scatter blocks
#define EPB 9375          // edges per hist/scatter block (64*9375 == 600000)
#define BINCAP 4608       // max edges per bin (avg 3061, huge headroom)

typedef unsigned short bf16_t;
typedef __attribute__((ext_vector_type(8))) short short8v;
typedef __attribute__((ext_vector_type(8))) unsigned short ushort8v;
typedef __attribute__((ext_vector_type(4))) float f32x4;

__device__ inline float bf2f(bf16_t u) {
    union { unsigned int i; float f; } c;
    c.i = ((unsigned int)u) << 16;
    return c.f;
}
__device__ inline bf16_t f2bf(float f) {  // round-to-nearest-even
    union { float f; unsigned int i; } c;
    c.f = f;
    unsigned int lsb = (c.i >> 16) & 1;
    c.i += 0x7fffu + lsb;
    return (bf16_t)(c.i >> 16);
}

// ---------------------------------------------------------------------------
// K1: block 0 = FULL weight chain in one block (Wc in LDS -> bc -> Mbf, v1);
//     blocks [1, 1+NHB) = passA coarse histogram of dst>>8 -> cnt2.
// ---------------------------------------------------------------------------
__global__ __launch_bounds__(1024)
void k_prep(const float* __restrict__ w1, const float* __restrict__ b1,
            const float* __restrict__ w2, const float* __restrict__ b2,
            bf16_t* __restrict__ Mbf, float* __restrict__ v1g,
            float* __restrict__ bcg,
            const int* __restrict__ dst, int* __restrict__ cnt2) {
    int bid = blockIdx.x;
    int t = threadIdx.x;

    if (bid == 0) {
        __shared__ float WcS[128 * 128];  // 64KB
        __shared__ float bcS[128];
        // Wc = w2 @ w1
        for (int idx = t; idx < 16384; idx += 1024) {
            int p = idx >> 7, j = idx & 127;
            float s = 0.f;
            for (int o = 0; o < 128; ++o) s = fmaf(w2[p * 128 + o], w1[o * 128 + j], s);
            WcS[idx] = s;
        }
        if (t < 128) {
            float s = b2[t];
            for (int o = 0; o < 128; ++o) s = fmaf(w2[t * 128 + o], b1[o], s);
            bcS[t] = s;
            bcg[t] = s;
        }
        __syncthreads();
        // Mbf[p][k] = sum_o Wc[p][o] * Wc[o][k]  (bf16, B-operand layout)
        for (int idx = t; idx < 16384; idx += 1024) {
            int p = idx >> 7, k = idx & 127;
            float s = 0.f;
            for (int o = 0; o < 128; ++o) s = fmaf(WcS[p * 128 + o], WcS[o * 128 + k], s);
            Mbf[idx] = f2bf(s);
        }
        if (t < 128) {
            float s = 0.f;
            for (int o = 0; o < 128; ++o) s = fmaf(WcS[t * 128 + o], bcS[o], s);
            v1g[t] = s;
        }
        return;
    }

    // ---- histogram role ----
    __shared__ int hist[NBINS];
    int hb = bid - 1;
    for (int b = t; b < NBINS; b += 1024) hist[b] = 0;
    __syncthreads();
    int e0 = hb * EPB;
    for (int e = e0 + t; e < e0 + EPB; e += 1024) atomicAdd(&hist[dst[e] >> 8], 1);
    __syncthreads();
    for (int b = t; b < NBINS; b += 1024) cnt2[b * NHB + hb] = hist[b];
}

// ---------------------------------------------------------------------------
// K2: blocks [0, GEMM_BLOCKS) = MFMA GEMM g = x*M; blocks [GEMM_BLOCKS,+NHB)
// = passB: derives its own gofs column from cnt2 (row sums + 2 wave scans),
// LDS counting-sort of its edges by bin, then GROUPED flush into ebuf.
// ---------------------------------------------------------------------------
__global__ __launch_bounds__(256, 4)
void k_mainB(const float* __restrict__ X, const bf16_t* __restrict__ Mbf,
             bf16_t* __restrict__ G,
             const int* __restrict__ src, const int* __restrict__ dst,
             const int* __restrict__ cnt2, unsigned int* __restrict__ ebuf) {
    __shared__ __align__(16) unsigned char smem[EPB * 4 + 3 * NBINS * 4 + 16];
    const int bid = blockIdx.x;
    const int tid = threadIdx.x;

    if (bid >= GEMM_BLOCKS) {
        // ---- passB role ----
        unsigned int* pairs = (unsigned int*)smem;
        int* cur  = (int*)(smem + EPB * 4);
        int* lofs = cur + NBINS;
        int* gofs = lofs + NBINS;
        int* wt4  = gofs + NBINS;  // 4 ints
        int hb = bid - GEMM_BLOCKS;
        int lane = tid & 63, wv = tid >> 6;

        // per-bin: total over all columns (btot), prefix of own column (colpre)
        int c = 0, colpre = 0, btot = 0;
        if (tid < NBINS) {
            const int4* row = (const int4*)(cnt2 + tid * NHB);
            for (int h4 = 0; h4 < NHB / 4; ++h4) {
                int4 w = row[h4];
                btot += w.x + w.y + w.z + w.w;
                int base = h4 * 4;
                if (base + 0 < hb) colpre += w.x;
                if (base + 1 < hb) colpre += w.y;
                if (base + 2 < hb) colpre += w.z;
                if (base + 3 < hb) colpre += w.w;
            }
            c = cnt2[tid * NHB + hb];
        }

        // scan 1: exclusive scan of btot -> global bin bases
        int incl = btot;
#pragma unroll
        for (int o = 1; o < 64; o <<= 1) {
            int u = __shfl_up(incl, o);
            if (lane >= o) incl += u;
        }
        if (lane == 63) wt4[wv] = incl;
        __syncthreads();
        if (tid == 0) {
            int r = 0;
            for (int w = 0; w < 4; ++w) { int x = wt4[w]; wt4[w] = r; r += x; }
        }
        __syncthreads();
        if (tid < NBINS) gofs[tid] = incl - btot + wt4[wv] + colpre;
        __syncthreads();  // before wt4 reuse

        // scan 2: exclusive scan of own-column counts -> local layout
        int incl2 = c;
#pragma unroll
        for (int o = 1; o < 64; o <<= 1) {
            int u = __shfl_up(incl2, o);
            if (lane >= o) incl2 += u;
        }
        if (lane == 63) wt4[wv] = incl2;
        __syncthreads();
        if (tid == 0) {
            int r = 0;
            for (int w = 0; w < 4; ++w) { int x = wt4[w]; wt4[w] = r; r += x; }
        }
        __syncthreads();
        if (tid < NBINS) {
            int e = incl2 - c + wt4[wv];
            lofs[tid] = e;
            cur[tid] = e;
        }
        __syncthreads();

        // LDS counting-sort by bin
        int e0 = hb * EPB;
        for (int e = e0 + tid; e < e0 + EPB; e += 256) {
            int d = dst[e];
            int s = src[e];
            unsigned int p = ((unsigned int)d << 16) | (unsigned int)s;
            int slot = atomicAdd(&cur[d >> 8], 1);  // LDS atomic
            pairs[slot] = p;
        }
        __syncthreads();

        // grouped flush
        for (int i = tid; i < EPB; i += 256) {
            unsigned int p = pairs[i];
            int b = p >> 24;
            ebuf[gofs[b] + (i - lofs[b])] = p;
        }
        return;
    }

    // ---- GEMM role ----
    unsigned short* Xs = (unsigned short*)smem;  // [64][128] bf16, swizzled
    const int row0 = bid * 64;

    for (int idx = tid; idx < 1024; idx += 256) {
        int r = idx >> 4, c = idx & 15;
        int grow = row0 + r;
        float4 va = {0.f, 0.f, 0.f, 0.f}, vb = {0.f, 0.f, 0.f, 0.f};
        if (grow < N_NODES) {
            const float4* xr = (const float4*)(X + (size_t)grow * F);
            va = xr[2 * c];
            vb = xr[2 * c + 1];
        }
        ushort8v u;
        u[0] = f2bf(va.x); u[1] = f2bf(va.y); u[2] = f2bf(va.z); u[3] = f2bf(va.w);
        u[4] = f2bf(vb.x); u[5] = f2bf(vb.y); u[6] = f2bf(vb.z); u[7] = f2bf(vb.w);
        *(ushort8v*)&Xs[r * 128 + (((c ^ (r & 7)) << 3))] = u;
    }
    __syncthreads();

    const int wid = tid >> 6;
    const int lane = tid & 63;
    const int wr = wid >> 1;
    const int wc = wid & 1;
    const int l15 = lane & 15;
    const int l4 = lane >> 4;
    const int sw = (l15 & 7);

    f32x4 acc[2][4] = {};

#pragma unroll
    for (int kc = 0; kc < 4; ++kc) {
        const int cS = ((kc * 4 + l4) ^ sw) << 3;
        short8v a0 = *(const short8v*)&Xs[(wr * 32 + 0 * 16 + l15) * 128 + cS];
        short8v a1 = *(const short8v*)&Xs[(wr * 32 + 1 * 16 + l15) * 128 + cS];
        const bf16_t* mb = Mbf + (size_t)(wc * 64 + l15) * F + kc * 32 + 8 * l4;
        short8v b0 = *(const short8v*)(mb + 0 * 16 * F);
        short8v b1 = *(const short8v*)(mb + 1 * 16 * F);
        short8v b2 = *(const short8v*)(mb + 2 * 16 * F);
        short8v b3 = *(const short8v*)(mb + 3 * 16 * F);
        acc[0][0] = __builtin_amdgcn_mfma_f32_16x16x32_bf16(a0, b0, acc[0][0], 0, 0, 0);
        acc[0][1] = __builtin_amdgcn_mfma_f32_16x16x32_bf16(a0, b1, acc[0][1], 0, 0, 0);
        acc[0][2] = __builtin_amdgcn_mfma_f32_16x16x32_bf16(a0, b2, acc[0][2], 0, 0, 0);
        acc[0][3] = __builtin_amdgcn_mfma_f32_16x16x32_bf16(a0, b3, acc[0][3], 0, 0, 0);
        acc[1][0] = __builtin_amdgcn_mfma_f32_16x16x32_bf16(a1, b0, acc[1][0], 0, 0, 0);
        acc[1][1] = __builtin_amdgcn_mfma_f32_16x16x32_bf16(a1, b1, acc[1][1], 0, 0, 0);
        acc[1][2] = __builtin_amdgcn_mfma_f32_16x16x32_bf16(a1, b2, acc[1][2], 0, 0, 0);
        acc[1][3] = __builtin_amdgcn_mfma_f32_16x16x32_bf16(a1, b3, acc[1][3], 0, 0, 0);
    }

#pragma unroll
    for (int mt = 0; mt < 2; ++mt) {
#pragma unroll
        for (int nt = 0; nt < 4; ++nt) {
#pragma unroll
            for (int r = 0; r < 4; ++r) {
                int grow = row0 + wr * 32 + mt * 16 + l4 * 4 + r;
                if (grow < N_NODES) {
                    int gcol = wc * 64 + nt * 16 + l15;
                    G[(size_t)grow * F + gcol] = f2bf(acc[mt][nt][r]);
                }
            }
        }
    }
}

// ---------------------------------------------------------------------------
// K3: per-bin finalize + first aggregation. Derives r0/m from cnt2 (block
// reduction), histogram + scan -> cnt/rofs, counting sort -> ssrc, per-node
// SORT-BY-SRC (insertion sort, canonical csr + gather locality), csr write,
// then a1[n] = g[n] + sum g[ssrc] reading edge list from LDS.
// ---------------------------------------------------------------------------
__global__ __launch_bounds__(1024)
void k_fineagg(const unsigned int* __restrict__ ebuf, const int* __restrict__ cnt2,
               const bf16_t* __restrict__ g,
               int* __restrict__ cnt, int* __restrict__ rofs,
               unsigned short* __restrict__ csr, bf16_t* __restrict__ a1) {
    __shared__ unsigned int pairs[BINCAP];
    __shared__ unsigned short ssrc[BINCAP];
    __shared__ int hcnt[256];
    __shared__ int hofs[256];
    __shared__ int cur[256];
    __shared__ int wtot[16];
    __shared__ int r0s, ms;
    const int b = blockIdx.x;
    const int t = threadIdx.x;
    const int lane = t & 63, wv = t >> 6;

    // r0 = sum cnt2[0 .. b*NHB); m = sum cnt2[b*NHB .. +NHB)
    const int lim = b * NHB;
    int part = 0;
    for (int idx = t; idx < lim; idx += 1024) part += cnt2[idx];
#pragma unroll
    for (int o = 32; o; o >>= 1) part += __shfl_xor(part, o);
    if (lane == 0) wtot[wv] = part;
    int mv = 0;
    if (t < 64) {
        mv = cnt2[lim + t];
#pragma unroll
        for (int o = 32; o; o >>= 1) mv += __shfl_xor(mv, o);
    }
    __syncthreads();
    if (t == 0) {
        int r = 0;
        for (int w = 0; w < 16; ++w) r += wtot[w];
        r0s = r;
        ms = mv;
    }
    __syncthreads();
    const int r0 = r0s;
    const int m = ms;

    for (int i = t; i < m; i += 1024) pairs[i] = ebuf[r0 + i];
    if (t < 256) hcnt[t] = 0;
    __syncthreads();
    for (int i = t; i < m; i += 1024) atomicAdd(&hcnt[(pairs[i] >> 16) & 255], 1);
    __syncthreads();

    int v = 0, incl = 0;
    if (t < 256) {
        v = hcnt[t];
        incl = v;
#pragma unroll
        for (int o = 1; o < 64; o <<= 1) {
            int u = __shfl_up(incl, o);
            if (lane >= o) incl += u;
        }
        if (lane == 63) wtot[wv] = incl;
    }
    __syncthreads();
    if (t == 0) {
        int r = 0;
        for (int w = 0; w < 4; ++w) { int x = wtot[w]; wtot[w] = r; r += x; }
    }
    __syncthreads();
    if (t < 256) {
        int excl = incl - v + wtot[wv];
        hofs[t] = excl;
        cur[t] = excl;
        int node = b * 256 + t;
        if (node < N_NODES) { cnt[node] = v; rofs[node] = r0 + excl; }
        else if (node == N_NODES) rofs[node] = N_EDGES;
    }
    __syncthreads();

    for (int i = t; i < m; i += 1024) {
        unsigned int u = pairs[i];
        int d8 = (u >> 16) & 255;
        int slot = atomicAdd(&cur[d8], 1);  // LDS atomic
        ssrc[slot] = (unsigned short)(u & 0xFFFF);
    }
    __syncthreads();

    // per-node insertion sort by src (canonical order + gather locality)
    if (t < 256) {
        int beg = hofs[t], n = hcnt[t];
        for (int i = 1; i < n; ++i) {
            unsigned short key = ssrc[beg + i];
            int j = i - 1;
            while (j >= 0 && ssrc[beg + j] > key) {
                ssrc[beg + j + 1] = ssrc[beg + j];
                --j;
            }
            ssrc[beg + j + 1] = key;
        }
    }
    __syncthreads();
    for (int i = t; i < m; i += 1024) csr[r0 + i] = ssrc[i];

    // ---- aggregation for this bin's nodes (edge list in LDS) ----
    const int lane16 = t & 15;
    const int grp = t >> 4;  // 0..63
    for (int ln = grp; ln < 256; ln += 64) {
        int node = b * 256 + ln;
        if (node >= N_NODES) continue;
        int deg = hcnt[ln];
        int rl = hofs[ln];

        ushort8v u = ((const ushort8v*)(g + (size_t)node * F))[lane16];
        float a0 = bf2f(u[0]), a1_ = bf2f(u[1]), a2 = bf2f(u[2]), a3 = bf2f(u[3]);
        float a4 = bf2f(u[4]), a5 = bf2f(u[5]), a6 = bf2f(u[6]), a7 = bf2f(u[7]);

        int i = 0;
        for (; i + 4 <= deg; i += 4) {
            int s0 = ssrc[rl + i], s1 = ssrc[rl + i + 1];
            int s2 = ssrc[rl + i + 2], s3 = ssrc[rl + i + 3];
            ushort8v u0 = ((const ushort8v*)(g + (size_t)s0 * F))[lane16];
            ushort8v u1 = ((const ushort8v*)(g + (size_t)s1 * F))[lane16];
            ushort8v u2 = ((const ushort8v*)(g + (size_t)s2 * F))[lane16];
            ushort8v u3 = ((const ushort8v*)(g + (size_t)s3 * F))[lane16];
            a0 += bf2f(u0[0]) + bf2f(u1[0]) + bf2f(u2[0]) + bf2f(u3[0]);
            a1_ += bf2f(u0[1]) + bf2f(u1[1]) + bf2f(u2[1]) + bf2f(u3[1]);
            a2 += bf2f(u0[2]) + bf2f(u1[2]) + bf2f(u2[2]) + bf2f(u3[2]);
            a3 += bf2f(u0[3]) + bf2f(u1[3]) + bf2f(u2[3]) + bf2f(u3[3]);
            a4 += bf2f(u0[4]) + bf2f(u1[4]) + bf2f(u2[4]) + bf2f(u3[4]);
            a5 += bf2f(u0[5]) + bf2f(u1[5]) + bf2f(u2[5]) + bf2f(u3[5]);
            a6 += bf2f(u0[6]) + bf2f(u1[6]) + bf2f(u2[6]) + bf2f(u3[6]);
            a7 += bf2f(u0[7]) + bf2f(u1[7]) + bf2f(u2[7]) + bf2f(u3[7]);
        }
        for (; i < deg; ++i) {
            int s = ssrc[rl + i];
            ushort8v uv = ((const ushort8v*)(g + (size_t)s * F))[lane16];
            a0 += bf2f(uv[0]); a1_ += bf2f(uv[1]); a2 += bf2f(uv[2]); a3 += bf2f(uv[3]);
            a4 += bf2f(uv[4]); a5 += bf2f(uv[5]); a6 += bf2f(uv[6]); a7 += bf2f(uv[7]);
        }
        ushort8v o;
        o[0] = f2bf(a0); o[1] = f2bf(a1_); o[2] = f2bf(a2); o[3] = f2bf(a3);
        o[4] = f2bf(a4); o[5] = f2bf(a5); o[6] = f2bf(a6); o[7] = f2bf(a7);
        ((ushort8v*)(a1 + (size_t)node * F))[lane16] = o;
    }
}

// ---------------------------------------------------------------------------
// K4: out[n] = log_softmax( (S*a1)[n] + sd_n*v1 + d_n*bc ), sd inline via
// cnt gathers; softmax reduced over the 16-lane group.
// ---------------------------------------------------------------------------
__global__ __launch_bounds__(256)
void k_agg_ep(const bf16_t* __restrict__ H, const int* __restrict__ rofs,
              const unsigned short* __restrict__ csr, const int* __restrict__ cnt,
              const float* __restrict__ v1, const float* __restrict__ bc,
              float* __restrict__ O, int n_rows) {
    int tid = threadIdx.x;
    int lane = tid & 15;
    int node = blockIdx.x * 16 + (tid >> 4);
    if (node >= n_rows) return;

    int r0 = rofs[node];
    int deg = rofs[node + 1] - r0;

    ushort8v u = ((const ushort8v*)(H + (size_t)node * F))[lane];
    float a0 = bf2f(u[0]), a1 = bf2f(u[1]), a2 = bf2f(u[2]), a3 = bf2f(u[3]);
    float a4 = bf2f(u[4]), a5 = bf2f(u[5]), a6 = bf2f(u[6]), a7 = bf2f(u[7]);

    const unsigned short* bk = csr + r0;

    int sdi = (lane == 0) ? (deg + 1) : 0;
    for (int j = lane; j < deg; j += 16) sdi += cnt[bk[j]] + 1;

    int i = 0;
    for (; i + 4 <= deg; i += 4) {
        int s0 = bk[i + 0], s1 = bk[i + 1], s2 = bk[i + 2], s3 = bk[i + 3];
        ushort8v u0 = ((const ushort8v*)(H + (size_t)s0 * F))[lane];
        ushort8v u1 = ((const ushort8v*)(H + (size_t)s1 * F))[lane];
        ushort8v u2 = ((const ushort8v*)(H + (size_t)s2 * F))[lane];
        ushort8v u3 = ((const ushort8v*)(H + (size_t)s3 * F))[lane];
        a0 += bf2f(u0[0]) + bf2f(u1[0]) + bf2f(u2[0]) + bf2f(u3[0]);
        a1 += bf2f(u0[1]) + bf2f(u1[1]) + bf2f(u2[1]) + bf2f(u3[1]);
        a2 += bf2f(u0[2]) + bf2f(u1[2]) + bf2f(u2[2]) + bf2f(u3[2]);
        a3 += bf2f(u0[3]) + bf2f(u1[3]) + bf2f(u2[3]) + bf2f(u3[3]);
        a4 += bf2f(u0[4]) + bf2f(u1[4]) + bf2f(u2[4]) + bf2f(u3[4]);
        a5 += bf2f(u0[5]) + bf2f(u1[5]) + bf2f(u2[5]) + bf2f(u3[5]);
        a6 += bf2f(u0[6]) + bf2f(u1[6]) + bf2f(u2[6]) + bf2f(u3[6]);
        a7 += bf2f(u0[7]) + bf2f(u1[7]) + bf2f(u2[7]) + bf2f(u3[7]);
    }
    for (; i < deg; ++i) {
        ushort8v uv = ((const ushort8v*)(H + (size_t)bk[i] * F))[lane];
        a0 += bf2f(uv[0]); a1 += bf2f(uv[1]); a2 += bf2f(uv[2]); a3 += bf2f(uv[3]);
        a4 += bf2f(uv[4]); a5 += bf2f(uv[5]); a6 += bf2f(uv[6]); a7 += bf2f(uv[7]);
    }

#pragma unroll
    for (int o = 8; o; o >>= 1) sdi += __shfl_xor(sdi, o);
    float sdn = (float)sdi;
    float dn = (float)(deg + 1);
    float4 v1a = ((const float4*)v1)[2 * lane], v1b = ((const float4*)v1)[2 * lane + 1];
    float4 bca = ((const float4*)bc)[2 * lane], bcb = ((const float4*)bc)[2 * lane + 1];
    a0 += sdn * v1a.x + dn * bca.x;
    a1 += sdn * v1a.y + dn * bca.y;
    a2 += sdn * v1a.z + dn * bca.z;
    a3 += sdn * v1a.w + dn * bca.w;
    a4 += sdn * v1b.x + dn * bcb.x;
    a5 += sdn * v1b.y + dn * bcb.y;
    a6 += sdn * v1b.z + dn * bcb.z;
    a7 += sdn * v1b.w + dn * bcb.w;

    float m = fmaxf(fmaxf(fmaxf(a0, a1), fmaxf(a2, a3)),
                    fmaxf(fmaxf(a4, a5), fmaxf(a6, a7)));
#pragma unroll
    for (int o = 8; o; o >>= 1) m = fmaxf(m, __shfl_xor(m, o));
    float s = expf(a0 - m) + expf(a1 - m) + expf(a2 - m) + expf(a3 - m)
            + expf(a4 - m) + expf(a5 - m) + expf(a6 - m) + expf(a7 - m);
#pragma unroll
    for (int o = 8; o; o >>= 1) s += __shfl_xor(s, o);
    float lse = m + logf(s);
    float4 oa, ob;
    oa.x = a0 - lse; oa.y = a1 - lse; oa.z = a2 - lse; oa.w = a3 - lse;
    ob.x = a4 - lse; ob.y = a5 - lse; ob.z = a6 - lse; ob.w = a7 - lse;
    ((float4*)(O + (size_t)node * F))[2 * lane] = oa;
    ((float4*)(O + (size_t)node * F))[2 * lane + 1] = ob;
}

extern "C" void kernel_launch(void* const* d_in, const int* in_sizes, int n_in,
                              void* d_out, int out_size, void* d_ws, size_t ws_size,
                              hipStream_t stream) {
    const float* x  = (const float*)d_in[0];
    const int* ei   = (const int*)d_in[1];
    const float* w1 = (const float*)d_in[2];
    const float* b1 = (const float*)d_in[3];
    const float* w2 = (const float*)d_in[4];
    const float* b2 = (const float*)d_in[5];
    float* out = (float*)d_out;

    const int* src = ei;
    const int* dst = ei + N_EDGES;

    // workspace layout (float offsets, 16B aligned)
    float* ws        = (float*)d_ws;
    float* bc        = ws;                          // 128
    float* v1        = ws + 128;                    // 128
    bf16_t* Mbf      = (bf16_t*)(ws + 256);         // 16384 bf16 (8192 f)
    int*   cnt       = (int*)(ws + 8448);           // 50048
    int*   rofs      = (int*)(ws + 58496);          // 50001 (pad 50048)
    int*   cnt2      = (int*)(ws + 108544);         // 12544 (pad 12800)
    unsigned int* ebuf = (unsigned int*)(ws + 121344);     // 600000 u32
    unsigned short* csr = (unsigned short*)(ws + 721344);  // 600000 u16 (300000 f)
    bf16_t* g        = (bf16_t*)(ws + 1021344);     // 6.4M bf16 (3.2M f)
    bf16_t* a1       = (bf16_t*)(ws + 4221344);     // 6.4M bf16

    const int node_grid = (N_NODES + 15) / 16;  // 3125

    // K1: full weight chain (1 block) || coarse histogram (NHB blocks)
    k_prep<<<1 + NHB, 1024, 0, stream>>>(w1, b1, w2, b2, Mbf, v1, bc, dst, cnt2);
    // K2: g = x*M (MFMA) || passB self-scanned LDS-sorted grouped scatter
    k_mainB<<<GEMM_BLOCKS + NHB, 256, 0, stream>>>(x, Mbf, g, src, dst, cnt2, ebuf);
    // K3: per-bin sort (by dst, then src) -> cnt/rofs/csr + a1 = S*g
    k_fineagg<<<NBINS, 1024, 0, stream>>>(ebuf, cnt2, g, cnt, rofs, csr, a1);
    // K4: out = log_softmax(S*a1 + sd*v1^T + d*bc^T)
    k_agg_ep<<<node_grid, 256, 0, stream>>>(a1, rofs, csr, cnt, v1, bc, out, N_NODES);
}

// Round 13
// 139.953 us; speedup vs baseline: 2.7994x; 2.7994x over previous
//
#include <hip/hip_runtime.h>
#include <hip/hip_bf16.h>

#define N_NODES 50000
#define N_EDGES 600000
#define F 128

#define GEMM_BLOCKS 782   // ceil(50000/64)
#define NBINS 196         // ceil(50000/256), bin = dst >> 8
#define NHB 64            // histogram/scatter blocks
#define EPB 9375          // edges per hist/scatter block (64*9375 == 600000)
#define BINCAP 4608       // max edges per bin (avg 3061, huge headroom)

typedef unsigned short bf16_t;
typedef __attribute__((ext_vector_type(8))) short short8v;
typedef __attribute__((ext_vector_type(8))) unsigned short ushort8v;
typedef __attribute__((ext_vector_type(4))) float f32x4;

__device__ inline float bf2f(bf16_t u) {
    union { unsigned int i; float f; } c;
    c.i = ((unsigned int)u) << 16;
    return c.f;
}
__device__ inline bf16_t f2bf(float f) {  // round-to-nearest-even
    union { float f; unsigned int i; } c;
    c.f = f;
    unsigned int lsb = (c.i >> 16) & 1;
    c.i += 0x7fffu + lsb;
    return (bf16_t)(c.i >> 16);
}

// ---------------------------------------------------------------------------
// K1: blocks [0,128) = weight fusion (Wc = w2@w1, bc = w2@b1+b2), one block
// per output row p -> 128-way block parallelism, short latency chains;
// blocks [128,128+NHB) = passA coarse histogram of dst>>8 -> cnt2.
// ---------------------------------------------------------------------------
__global__ __launch_bounds__(256)
void k_prep(const float* __restrict__ w1, const float* __restrict__ b1,
            const float* __restrict__ w2, const float* __restrict__ b2,
            float* __restrict__ Wc, float* __restrict__ bc,
            const int* __restrict__ dst, int* __restrict__ cnt2) {
    __shared__ int hist[NBINS];
    int bid = blockIdx.x;
    int tid = threadIdx.x;
    if (bid < 128) {
        int p = bid;
        if (tid < 128) {
            int j = tid;
            float s = 0.f;
            for (int o = 0; o < F; ++o) s = fmaf(w2[p * F + o], w1[o * F + j], s);
            Wc[p * F + j] = s;
            if (j == 0) {
                float t = b2[p];
                for (int o = 0; o < F; ++o) t = fmaf(w2[p * F + o], b1[o], t);
                bc[p] = t;
            }
        }
        return;
    }
    int hb = bid - 128;
    for (int b = tid; b < NBINS; b += 256) hist[b] = 0;
    __syncthreads();
    int e0 = hb * EPB;
    for (int e = e0 + tid; e < e0 + EPB; e += 256) atomicAdd(&hist[dst[e] >> 8], 1);
    __syncthreads();
    for (int b = tid; b < NBINS; b += 256) cnt2[b * NHB + hb] = hist[b];
}

// ---------------------------------------------------------------------------
// K2 (16 blocks x 1024): Mbf[p][k] = (W^T W^T)[k][p] in bf16 (B-operand
// layout), 8 k-columns per block; v1 = Wc*bc on block 0.
// ---------------------------------------------------------------------------
__global__ __launch_bounds__(1024)
void k_mbf(const float* __restrict__ Wc, const float* __restrict__ bc,
           bf16_t* __restrict__ Mbf, float* __restrict__ v1) {
    int bid = blockIdx.x;
    int t = threadIdx.x;
    int kk = bid * 8 + (t >> 7);
    int p = t & 127;
    float s = 0.f;
    for (int o = 0; o < F; ++o) s = fmaf(Wc[p * F + o], Wc[o * F + kk], s);
    Mbf[p * F + kk] = f2bf(s);
    if (bid == 0 && t < 128) {
        float v = 0.f;
        for (int o = 0; o < F; ++o) v = fmaf(Wc[t * F + o], bc[o], v);
        v1[t] = v;
    }
}

// ---------------------------------------------------------------------------
// K3: blocks [0, GEMM_BLOCKS) = MFMA GEMM g = x*M; blocks [GEMM_BLOCKS,+NHB)
// = passB: derives its own gofs column from cnt2 (row sums + 2 wave scans),
// LDS counting-sort of its edges by bin, then GROUPED flush into ebuf.
// ---------------------------------------------------------------------------
__global__ __launch_bounds__(256, 4)
void k_mainB(const float* __restrict__ X, const bf16_t* __restrict__ Mbf,
             bf16_t* __restrict__ G,
             const int* __restrict__ src, const int* __restrict__ dst,
             const int* __restrict__ cnt2, unsigned int* __restrict__ ebuf) {
    __shared__ __align__(16) unsigned char smem[EPB * 4 + 3 * NBINS * 4 + 16];
    const int bid = blockIdx.x;
    const int tid = threadIdx.x;

    if (bid >= GEMM_BLOCKS) {
        // ---- passB role ----
        unsigned int* pairs = (unsigned int*)smem;
        int* cur  = (int*)(smem + EPB * 4);
        int* lofs = cur + NBINS;
        int* gofs = lofs + NBINS;
        int* wt4  = gofs + NBINS;  // 4 ints
        int hb = bid - GEMM_BLOCKS;
        int lane = tid & 63, wv = tid >> 6;

        int c = 0, colpre = 0, btot = 0;
        if (tid < NBINS) {
            const int4* row = (const int4*)(cnt2 + tid * NHB);
            for (int h4 = 0; h4 < NHB / 4; ++h4) {
                int4 w = row[h4];
                btot += w.x + w.y + w.z + w.w;
                int base = h4 * 4;
                if (base + 0 < hb) colpre += w.x;
                if (base + 1 < hb) colpre += w.y;
                if (base + 2 < hb) colpre += w.z;
                if (base + 3 < hb) colpre += w.w;
            }
            c = cnt2[tid * NHB + hb];
        }

        int incl = btot;
#pragma unroll
        for (int o = 1; o < 64; o <<= 1) {
            int u = __shfl_up(incl, o);
            if (lane >= o) incl += u;
        }
        if (lane == 63) wt4[wv] = incl;
        __syncthreads();
        if (tid == 0) {
            int r = 0;
            for (int w = 0; w < 4; ++w) { int x = wt4[w]; wt4[w] = r; r += x; }
        }
        __syncthreads();
        if (tid < NBINS) gofs[tid] = incl - btot + wt4[wv] + colpre;
        __syncthreads();

        int incl2 = c;
#pragma unroll
        for (int o = 1; o < 64; o <<= 1) {
            int u = __shfl_up(incl2, o);
            if (lane >= o) incl2 += u;
        }
        if (lane == 63) wt4[wv] = incl2;
        __syncthreads();
        if (tid == 0) {
            int r = 0;
            for (int w = 0; w < 4; ++w) { int x = wt4[w]; wt4[w] = r; r += x; }
        }
        __syncthreads();
        if (tid < NBINS) {
            int e = incl2 - c + wt4[wv];
            lofs[tid] = e;
            cur[tid] = e;
        }
        __syncthreads();

        int e0 = hb * EPB;
        for (int e = e0 + tid; e < e0 + EPB; e += 256) {
            int d = dst[e];
            int s = src[e];
            unsigned int p = ((unsigned int)d << 16) | (unsigned int)s;
            int slot = atomicAdd(&cur[d >> 8], 1);  // LDS atomic
            pairs[slot] = p;
        }
        __syncthreads();

        for (int i = tid; i < EPB; i += 256) {
            unsigned int p = pairs[i];
            int b = p >> 24;
            ebuf[gofs[b] + (i - lofs[b])] = p;
        }
        return;
    }

    // ---- GEMM role ----
    unsigned short* Xs = (unsigned short*)smem;  // [64][128] bf16, swizzled
    const int row0 = bid * 64;

    for (int idx = tid; idx < 1024; idx += 256) {
        int r = idx >> 4, c = idx & 15;
        int grow = row0 + r;
        float4 va = {0.f, 0.f, 0.f, 0.f}, vb = {0.f, 0.f, 0.f, 0.f};
        if (grow < N_NODES) {
            const float4* xr = (const float4*)(X + (size_t)grow * F);
            va = xr[2 * c];
            vb = xr[2 * c + 1];
        }
        ushort8v u;
        u[0] = f2bf(va.x); u[1] = f2bf(va.y); u[2] = f2bf(va.z); u[3] = f2bf(va.w);
        u[4] = f2bf(vb.x); u[5] = f2bf(vb.y); u[6] = f2bf(vb.z); u[7] = f2bf(vb.w);
        *(ushort8v*)&Xs[r * 128 + (((c ^ (r & 7)) << 3))] = u;
    }
    __syncthreads();

    const int wid = tid >> 6;
    const int lane = tid & 63;
    const int wr = wid >> 1;
    const int wc = wid & 1;
    const int l15 = lane & 15;
    const int l4 = lane >> 4;
    const int sw = (l15 & 7);

    f32x4 acc[2][4] = {};

#pragma unroll
    for (int kc = 0; kc < 4; ++kc) {
        const int cS = ((kc * 4 + l4) ^ sw) << 3;
        short8v a0 = *(const short8v*)&Xs[(wr * 32 + 0 * 16 + l15) * 128 + cS];
        short8v a1 = *(const short8v*)&Xs[(wr * 32 + 1 * 16 + l15) * 128 + cS];
        const bf16_t* mb = Mbf + (size_t)(wc * 64 + l15) * F + kc * 32 + 8 * l4;
        short8v b0 = *(const short8v*)(mb + 0 * 16 * F);
        short8v b1 = *(const short8v*)(mb + 1 * 16 * F);
        short8v b2 = *(const short8v*)(mb + 2 * 16 * F);
        short8v b3 = *(const short8v*)(mb + 3 * 16 * F);
        acc[0][0] = __builtin_amdgcn_mfma_f32_16x16x32_bf16(a0, b0, acc[0][0], 0, 0, 0);
        acc[0][1] = __builtin_amdgcn_mfma_f32_16x16x32_bf16(a0, b1, acc[0][1], 0, 0, 0);
        acc[0][2] = __builtin_amdgcn_mfma_f32_16x16x32_bf16(a0, b2, acc[0][2], 0, 0, 0);
        acc[0][3] = __builtin_amdgcn_mfma_f32_16x16x32_bf16(a0, b3, acc[0][3], 0, 0, 0);
        acc[1][0] = __builtin_amdgcn_mfma_f32_16x16x32_bf16(a1, b0, acc[1][0], 0, 0, 0);
        acc[1][1] = __builtin_amdgcn_mfma_f32_16x16x32_bf16(a1, b1, acc[1][1], 0, 0, 0);
        acc[1][2] = __builtin_amdgcn_mfma_f32_16x16x32_bf16(a1, b2, acc[1][2], 0, 0, 0);
        acc[1][3] = __builtin_amdgcn_mfma_f32_16x16x32_bf16(a1, b3, acc[1][3], 0, 0, 0);
    }

#pragma unroll
    for (int mt = 0; mt < 2; ++mt) {
#pragma unroll
        for (int nt = 0; nt < 4; ++nt) {
#pragma unroll
            for (int r = 0; r < 4; ++r) {
                int grow = row0 + wr * 32 + mt * 16 + l4 * 4 + r;
                if (grow < N_NODES) {
                    int gcol = wc * 64 + nt * 16 + l15;
                    G[(size_t)grow * F + gcol] = f2bf(acc[mt][nt][r]);
                }
            }
        }
    }
}

// ---------------------------------------------------------------------------
// K4: per-bin finalize + first aggregation. Derives r0/m from cnt2 (block
// reduction), histogram + scan -> cnt/rofs, counting sort -> ssrc, per-node
// sort-by-src (canonical csr + gather locality), csr write, then
// a1[n] = g[n] + sum g[ssrc] reading edge list from LDS.
// ---------------------------------------------------------------------------
__global__ __launch_bounds__(1024)
void k_fineagg(const unsigned int* __restrict__ ebuf, const int* __restrict__ cnt2,
               const bf16_t* __restrict__ g,
               int* __restrict__ cnt, int* __restrict__ rofs,
               unsigned short* __restrict__ csr, bf16_t* __restrict__ a1) {
    __shared__ unsigned int pairs[BINCAP];
    __shared__ unsigned short ssrc[BINCAP];
    __shared__ int hcnt[256];
    __shared__ int hofs[256];
    __shared__ int cur[256];
    __shared__ int wtot[16];
    __shared__ int r0s, ms;
    const int b = blockIdx.x;
    const int t = threadIdx.x;
    const int lane = t & 63, wv = t >> 6;

    const int lim = b * NHB;
    int part = 0;
    for (int idx = t; idx < lim; idx += 1024) part += cnt2[idx];
#pragma unroll
    for (int o = 32; o; o >>= 1) part += __shfl_xor(part, o);
    if (lane == 0) wtot[wv] = part;
    int mv = 0;
    if (t < 64) {
        mv = cnt2[lim + t];
#pragma unroll
        for (int o = 32; o; o >>= 1) mv += __shfl_xor(mv, o);
    }
    __syncthreads();
    if (t == 0) {
        int r = 0;
        for (int w = 0; w < 16; ++w) r += wtot[w];
        r0s = r;
        ms = mv;
    }
    __syncthreads();
    const int r0 = r0s;
    const int m = ms;

    for (int i = t; i < m; i += 1024) pairs[i] = ebuf[r0 + i];
    if (t < 256) hcnt[t] = 0;
    __syncthreads();
    for (int i = t; i < m; i += 1024) atomicAdd(&hcnt[(pairs[i] >> 16) & 255], 1);
    __syncthreads();

    int v = 0, incl = 0;
    if (t < 256) {
        v = hcnt[t];
        incl = v;
#pragma unroll
        for (int o = 1; o < 64; o <<= 1) {
            int u = __shfl_up(incl, o);
            if (lane >= o) incl += u;
        }
        if (lane == 63) wtot[wv] = incl;
    }
    __syncthreads();
    if (t == 0) {
        int r = 0;
        for (int w = 0; w < 4; ++w) { int x = wtot[w]; wtot[w] = r; r += x; }
    }
    __syncthreads();
    if (t < 256) {
        int excl = incl - v + wtot[wv];
        hofs[t] = excl;
        cur[t] = excl;
        int node = b * 256 + t;
        if (node < N_NODES) { cnt[node] = v; rofs[node] = r0 + excl; }
        else if (node == N_NODES) rofs[node] = N_EDGES;
    }
    __syncthreads();

    for (int i = t; i < m; i += 1024) {
        unsigned int u = pairs[i];
        int d8 = (u >> 16) & 255;
        int slot = atomicAdd(&cur[d8], 1);  // LDS atomic
        ssrc[slot] = (unsigned short)(u & 0xFFFF);
    }
    __syncthreads();

    if (t < 256) {
        int beg = hofs[t], n = hcnt[t];
        for (int i = 1; i < n; ++i) {
            unsigned short key = ssrc[beg + i];
            int j = i - 1;
            while (j >= 0 && ssrc[beg + j] > key) {
                ssrc[beg + j + 1] = ssrc[beg + j];
                --j;
            }
            ssrc[beg + j + 1] = key;
        }
    }
    __syncthreads();
    for (int i = t; i < m; i += 1024) csr[r0 + i] = ssrc[i];

    const int lane16 = t & 15;
    const int grp = t >> 4;  // 0..63
    for (int ln = grp; ln < 256; ln += 64) {
        int node = b * 256 + ln;
        if (node >= N_NODES) continue;
        int deg = hcnt[ln];
        int rl = hofs[ln];

        ushort8v u = ((const ushort8v*)(g + (size_t)node * F))[lane16];
        float a0 = bf2f(u[0]), a1_ = bf2f(u[1]), a2 = bf2f(u[2]), a3 = bf2f(u[3]);
        float a4 = bf2f(u[4]), a5 = bf2f(u[5]), a6 = bf2f(u[6]), a7 = bf2f(u[7]);

        int i = 0;
        for (; i + 4 <= deg; i += 4) {
            int s0 = ssrc[rl + i], s1 = ssrc[rl + i + 1];
            int s2 = ssrc[rl + i + 2], s3 = ssrc[rl + i + 3];
            ushort8v u0 = ((const ushort8v*)(g + (size_t)s0 * F))[lane16];
            ushort8v u1 = ((const ushort8v*)(g + (size_t)s1 * F))[lane16];
            ushort8v u2 = ((const ushort8v*)(g + (size_t)s2 * F))[lane16];
            ushort8v u3 = ((const ushort8v*)(g + (size_t)s3 * F))[lane16];
            a0 += bf2f(u0[0]) + bf2f(u1[0]) + bf2f(u2[0]) + bf2f(u3[0]);
            a1_ += bf2f(u0[1]) + bf2f(u1[1]) + bf2f(u2[1]) + bf2f(u3[1]);
            a2 += bf2f(u0[2]) + bf2f(u1[2]) + bf2f(u2[2]) + bf2f(u3[2]);
            a3 += bf2f(u0[3]) + bf2f(u1[3]) + bf2f(u2[3]) + bf2f(u3[3]);
            a4 += bf2f(u0[4]) + bf2f(u1[4]) + bf2f(u2[4]) + bf2f(u3[4]);
            a5 += bf2f(u0[5]) + bf2f(u1[5]) + bf2f(u2[5]) + bf2f(u3[5]);
            a6 += bf2f(u0[6]) + bf2f(u1[6]) + bf2f(u2[6]) + bf2f(u3[6]);
            a7 += bf2f(u0[7]) + bf2f(u1[7]) + bf2f(u2[7]) + bf2f(u3[7]);
        }
        for (; i < deg; ++i) {
            int s = ssrc[rl + i];
            ushort8v uv = ((const ushort8v*)(g + (size_t)s * F))[lane16];
            a0 += bf2f(uv[0]); a1_ += bf2f(uv[1]); a2 += bf2f(uv[2]); a3 += bf2f(uv[3]);
            a4 += bf2f(uv[4]); a5 += bf2f(uv[5]); a6 += bf2f(uv[6]); a7 += bf2f(uv[7]);
        }
        ushort8v o;
        o[0] = f2bf(a0); o[1] = f2bf(a1_); o[2] = f2bf(a2); o[3] = f2bf(a3);
        o[4] = f2bf(a4); o[5] = f2bf(a5); o[6] = f2bf(a6); o[7] = f2bf(a7);
        ((ushort8v*)(a1 + (size_t)node * F))[lane16] = o;
    }
}

// ---------------------------------------------------------------------------
// K5: out[n] = log_softmax( (S*a1)[n] + sd_n*v1 + d_n*bc ), sd inline via
// cnt gathers; softmax reduced over the 16-lane group.
// ---------------------------------------------------------------------------
__global__ __launch_bounds__(256)
void k_agg_ep(const bf16_t* __restrict__ H, const int* __restrict__ rofs,
              const unsigned short* __restrict__ csr, const int* __restrict__ cnt,
              const float* __restrict__ v1, const float* __restrict__ bc,
              float* __restrict__ O, int n_rows) {
    int tid = threadIdx.x;
    int lane = tid & 15;
    int node = blockIdx.x * 16 + (tid >> 4);
    if (node >= n_rows) return;

    int r0 = rofs[node];
    int deg = rofs[node + 1] - r0;

    ushort8v u = ((const ushort8v*)(H + (size_t)node * F))[lane];
    float a0 = bf2f(u[0]), a1 = bf2f(u[1]), a2 = bf2f(u[2]), a3 = bf2f(u[3]);
    float a4 = bf2f(u[4]), a5 = bf2f(u[5]), a6 = bf2f(u[6]), a7 = bf2f(u[7]);

    const unsigned short* bk = csr + r0;

    int sdi = (lane == 0) ? (deg + 1) : 0;
    for (int j = lane; j < deg; j += 16) sdi += cnt[bk[j]] + 1;

    int i = 0;
    for (; i + 4 <= deg; i += 4) {
        int s0 = bk[i + 0], s1 = bk[i + 1], s2 = bk[i + 2], s3 = bk[i + 3];
        ushort8v u0 = ((const ushort8v*)(H + (size_t)s0 * F))[lane];
        ushort8v u1 = ((const ushort8v*)(H + (size_t)s1 * F))[lane];
        ushort8v u2 = ((const ushort8v*)(H + (size_t)s2 * F))[lane];
        ushort8v u3 = ((const ushort8v*)(H + (size_t)s3 * F))[lane];
        a0 += bf2f(u0[0]) + bf2f(u1[0]) + bf2f(u2[0]) + bf2f(u3[0]);
        a1 += bf2f(u0[1]) + bf2f(u1[1]) + bf2f(u2[1]) + bf2f(u3[1]);
        a2 += bf2f(u0[2]) + bf2f(u1[2]) + bf2f(u2[2]) + bf2f(u3[2]);
        a3 += bf2f(u0[3]) + bf2f(u1[3]) + bf2f(u2[3]) + bf2f(u3[3]);
        a4 += bf2f(u0[4]) + bf2f(u1[4]) + bf2f(u2[4]) + bf2f(u3[4]);
        a5 += bf2f(u0[5]) + bf2f(u1[5]) + bf2f(u2[5]) + bf2f(u3[5]);
        a6 += bf2f(u0[6]) + bf2f(u1[6]) + bf2f(u2[6]) + bf2f(u3[6]);
        a7 += bf2f(u0[7]) + bf2f(u1[7]) + bf2f(u2[7]) + bf2f(u3[7]);
    }
    for (; i < deg; ++i) {
        ushort8v uv = ((const ushort8v*)(H + (size_t)bk[i] * F))[lane];
        a0 += bf2f(uv[0]); a1 += bf2f(uv[1]); a2 += bf2f(uv[2]); a3 += bf2f(uv[3]);
        a4 += bf2f(uv[4]); a5 += bf2f(uv[5]); a6 += bf2f(uv[6]); a7 += bf2f(uv[7]);
    }

#pragma unroll
    for (int o = 8; o; o >>= 1) sdi += __shfl_xor(sdi, o);
    float sdn = (float)sdi;
    float dn = (float)(deg + 1);
    float4 v1a = ((const float4*)v1)[2 * lane], v1b = ((const float4*)v1)[2 * lane + 1];
    float4 bca = ((const float4*)bc)[2 * lane], bcb = ((const float4*)bc)[2 * lane + 1];
    a0 += sdn * v1a.x + dn * bca.x;
    a1 += sdn * v1a.y + dn * bca.y;
    a2 += sdn * v1a.z + dn * bca.z;
    a3 += sdn * v1a.w + dn * bca.w;
    a4 += sdn * v1b.x + dn * bcb.x;
    a5 += sdn * v1b.y + dn * bcb.y;
    a6 += sdn * v1b.z + dn * bcb.z;
    a7 += sdn * v1b.w + dn * bcb.w;

    float m = fmaxf(fmaxf(fmaxf(a0, a1), fmaxf(a2, a3)),
                    fmaxf(fmaxf(a4, a5), fmaxf(a6, a7)));
#pragma unroll
    for (int o = 8; o; o >>= 1) m = fmaxf(m, __shfl_xor(m, o));
    float s = expf(a0 - m) + expf(a1 - m) + expf(a2 - m) + expf(a3 - m)
            + expf(a4 - m) + expf(a5 - m) + expf(a6 - m) + expf(a7 - m);
#pragma unroll
    for (int o = 8; o; o >>= 1) s += __shfl_xor(s, o);
    float lse = m + logf(s);
    float4 oa, ob;
    oa.x = a0 - lse; oa.y = a1 - lse; oa.z = a2 - lse; oa.w = a3 - lse;
    ob.x = a4 - lse; ob.y = a5 - lse; ob.z = a6 - lse; ob.w = a7 - lse;
    ((float4*)(O + (size_t)node * F))[2 * lane] = oa;
    ((float4*)(O + (size_t)node * F))[2 * lane + 1] = ob;
}

extern "C" void kernel_launch(void* const* d_in, const int* in_sizes, int n_in,
                              void* d_out, int out_size, void* d_ws, size_t ws_size,
                              hipStream_t stream) {
    const float* x  = (const float*)d_in[0];
    const int* ei   = (const int*)d_in[1];
    const float* w1 = (const float*)d_in[2];
    const float* b1 = (const float*)d_in[3];
    const float* w2 = (const float*)d_in[4];
    const float* b2 = (const float*)d_in[5];
    float* out = (float*)d_out;

    const int* src = ei;
    const int* dst = ei + N_EDGES;

    // workspace layout (float offsets, 16B aligned)
    float* ws        = (float*)d_ws;
    float* Wc        = ws;                          // 16384
    float* bc        = ws + 16384;                  // 128
    float* v1        = ws + 16512;                  // 128
    bf16_t* Mbf      = (bf16_t*)(ws + 16640);       // 16384 bf16 (8192 f)
    int*   cnt       = (int*)(ws + 24832);          // 50048
    int*   rofs      = (int*)(ws + 74880);          // 50001 (pad 50048)
    int*   cnt2      = (int*)(ws + 124928);         // 12544 (pad 12800)
    unsigned int* ebuf = (unsigned int*)(ws + 137728);     // 600000 u32
    unsigned short* csr = (unsigned short*)(ws + 737728);  // 600000 u16 (300000 f)
    bf16_t* g        = (bf16_t*)(ws + 1037728);     // 6.4M bf16 (3.2M f)
    bf16_t* a1       = (bf16_t*)(ws + 4237728);     // 6.4M bf16

    const int node_grid = (N_NODES + 15) / 16;  // 3125

    // K1: weight fuse (128 blocks) || coarse histogram (NHB blocks)
    k_prep<<<128 + NHB, 256, 0, stream>>>(w1, b1, w2, b2, Wc, bc, dst, cnt2);
    // K2: Mbf + v1 (parallel, 16 blocks)
    k_mbf<<<16, 1024, 0, stream>>>(Wc, bc, Mbf, v1);
    // K3: g = x*M (MFMA) || passB self-scanned LDS-sorted grouped scatter
    k_mainB<<<GEMM_BLOCKS + NHB, 256, 0, stream>>>(x, Mbf, g, src, dst, cnt2, ebuf);
    // K4: per-bin sort (by dst, then src) -> cnt/rofs/csr + a1 = S*g
    k_fineagg<<<NBINS, 1024, 0, stream>>>(ebuf, cnt2, g, cnt, rofs, csr, a1);
    // K5: out = log_softmax(S*a1 + sd*v1^T + d*bc^T)
    k_agg_ep<<<node_grid, 256, 0, stream>>>(a1, rofs, csr, cnt, v1, bc, out, N_NODES);
}

// Round 14
// 118.871 us; speedup vs baseline: 3.2959x; 1.1774x over previous
//
#include <hip/hip_runtime.h>
#include <hip/hip_bf16.h>

#define N_NODES 50000
#define N_EDGES 600000
#define F 128

#define GEMM_BLOCKS 782   // ceil(50000/64)
#define NBINS 196         // ceil(50000/256), bin = dst >> 8
#define NHB 64            // histogram/scatter blocks
#define EPB 9375          // edges per hist/scatter block (64*9375 == 600000)
#define BINCAP 4608       // max edges per bin (avg 3061, huge headroom)

typedef unsigned short bf16_t;
typedef __attribute__((ext_vector_type(8))) short short8v;
typedef __attribute__((ext_vector_type(8))) unsigned short ushort8v;
typedef __attribute__((ext_vector_type(4))) float f32x4;

__device__ inline float bf2f(bf16_t u) {
    union { unsigned int i; float f; } c;
    c.i = ((unsigned int)u) << 16;
    return c.f;
}
__device__ inline bf16_t f2bf(float f) {  // round-to-nearest-even
    union { float f; unsigned int i; } c;
    c.f = f;
    unsigned int lsb = (c.i >> 16) & 1;
    c.i += 0x7fffu + lsb;
    return (bf16_t)(c.i >> 16);
}

// ---------------------------------------------------------------------------
// K1: blocks [0,128) = weight fusion (Wc = w2@w1, bc = w2@b1+b2), one block
// per output row p; blocks [128,128+NHB) = passA coarse histogram -> cnt2.
// ---------------------------------------------------------------------------
__global__ __launch_bounds__(256)
void k_prep(const float* __restrict__ w1, const float* __restrict__ b1,
            const float* __restrict__ w2, const float* __restrict__ b2,
            float* __restrict__ Wc, float* __restrict__ bc,
            const int* __restrict__ dst, int* __restrict__ cnt2) {
    __shared__ int hist[NBINS];
    int bid = blockIdx.x;
    int tid = threadIdx.x;
    if (bid < 128) {
        int p = bid;
        if (tid < 128) {
            int j = tid;
            float s = 0.f;
            for (int o = 0; o < F; ++o) s = fmaf(w2[p * F + o], w1[o * F + j], s);
            Wc[p * F + j] = s;
            if (j == 0) {
                float t = b2[p];
                for (int o = 0; o < F; ++o) t = fmaf(w2[p * F + o], b1[o], t);
                bc[p] = t;
            }
        }
        return;
    }
    int hb = bid - 128;
    for (int b = tid; b < NBINS; b += 256) hist[b] = 0;
    __syncthreads();
    int e0 = hb * EPB;
    for (int e = e0 + tid; e < e0 + EPB; e += 256) atomicAdd(&hist[dst[e] >> 8], 1);
    __syncthreads();
    for (int b = tid; b < NBINS; b += 256) cnt2[b * NHB + hb] = hist[b];
}

// ---------------------------------------------------------------------------
// K2 (16 blocks x 1024): Mbf[p][k] = (W^T W^T)[k][p] in bf16 (B-operand
// layout), 8 k-columns per block; v1 = Wc*bc on block 0.
// ---------------------------------------------------------------------------
__global__ __launch_bounds__(1024)
void k_mbf(const float* __restrict__ Wc, const float* __restrict__ bc,
           bf16_t* __restrict__ Mbf, float* __restrict__ v1) {
    int bid = blockIdx.x;
    int t = threadIdx.x;
    int kk = bid * 8 + (t >> 7);
    int p = t & 127;
    float s = 0.f;
    for (int o = 0; o < F; ++o) s = fmaf(Wc[p * F + o], Wc[o * F + kk], s);
    Mbf[p * F + kk] = f2bf(s);
    if (bid == 0 && t < 128) {
        float v = 0.f;
        for (int o = 0; o < F; ++o) v = fmaf(Wc[t * F + o], bc[o], v);
        v1[t] = v;
    }
}

// ---------------------------------------------------------------------------
// K3: blocks [0, GEMM_BLOCKS) = MFMA GEMM g = x*M; blocks [GEMM_BLOCKS,+NHB)
// = passB: derives its own gofs column from cnt2 (row sums + 2 wave scans),
// LDS counting-sort of its edges by bin, then GROUPED flush into ebuf.
// ---------------------------------------------------------------------------
__global__ __launch_bounds__(256, 4)
void k_mainB(const float* __restrict__ X, const bf16_t* __restrict__ Mbf,
             bf16_t* __restrict__ G,
             const int* __restrict__ src, const int* __restrict__ dst,
             const int* __restrict__ cnt2, unsigned int* __restrict__ ebuf) {
    __shared__ __align__(16) unsigned char smem[EPB * 4 + 3 * NBINS * 4 + 16];
    const int bid = blockIdx.x;
    const int tid = threadIdx.x;

    if (bid >= GEMM_BLOCKS) {
        // ---- passB role ----
        unsigned int* pairs = (unsigned int*)smem;
        int* cur  = (int*)(smem + EPB * 4);
        int* lofs = cur + NBINS;
        int* gofs = lofs + NBINS;
        int* wt4  = gofs + NBINS;  // 4 ints
        int hb = bid - GEMM_BLOCKS;
        int lane = tid & 63, wv = tid >> 6;

        int c = 0, colpre = 0, btot = 0;
        if (tid < NBINS) {
            const int4* row = (const int4*)(cnt2 + tid * NHB);
            for (int h4 = 0; h4 < NHB / 4; ++h4) {
                int4 w = row[h4];
                btot += w.x + w.y + w.z + w.w;
                int base = h4 * 4;
                if (base + 0 < hb) colpre += w.x;
                if (base + 1 < hb) colpre += w.y;
                if (base + 2 < hb) colpre += w.z;
                if (base + 3 < hb) colpre += w.w;
            }
            c = cnt2[tid * NHB + hb];
        }

        int incl = btot;
#pragma unroll
        for (int o = 1; o < 64; o <<= 1) {
            int u = __shfl_up(incl, o);
            if (lane >= o) incl += u;
        }
        if (lane == 63) wt4[wv] = incl;
        __syncthreads();
        if (tid == 0) {
            int r = 0;
            for (int w = 0; w < 4; ++w) { int x = wt4[w]; wt4[w] = r; r += x; }
        }
        __syncthreads();
        if (tid < NBINS) gofs[tid] = incl - btot + wt4[wv] + colpre;
        __syncthreads();

        int incl2 = c;
#pragma unroll
        for (int o = 1; o < 64; o <<= 1) {
            int u = __shfl_up(incl2, o);
            if (lane >= o) incl2 += u;
        }
        if (lane == 63) wt4[wv] = incl2;
        __syncthreads();
        if (tid == 0) {
            int r = 0;
            for (int w = 0; w < 4; ++w) { int x = wt4[w]; wt4[w] = r; r += x; }
        }
        __syncthreads();
        if (tid < NBINS) {
            int e = incl2 - c + wt4[wv];
            lofs[tid] = e;
            cur[tid] = e;
        }
        __syncthreads();

        int e0 = hb * EPB;
        for (int e = e0 + tid; e < e0 + EPB; e += 256) {
            int d = dst[e];
            int s = src[e];
            unsigned int p = ((unsigned int)d << 16) | (unsigned int)s;
            int slot = atomicAdd(&cur[d >> 8], 1);  // LDS atomic
            pairs[slot] = p;
        }
        __syncthreads();

        for (int i = tid; i < EPB; i += 256) {
            unsigned int p = pairs[i];
            int b = p >> 24;
            ebuf[gofs[b] + (i - lofs[b])] = p;
        }
        return;
    }

    // ---- GEMM role ----
    unsigned short* Xs = (unsigned short*)smem;  // [64][128] bf16, swizzled
    const int row0 = bid * 64;

    for (int idx = tid; idx < 1024; idx += 256) {
        int r = idx >> 4, c = idx & 15;
        int grow = row0 + r;
        float4 va = {0.f, 0.f, 0.f, 0.f}, vb = {0.f, 0.f, 0.f, 0.f};
        if (grow < N_NODES) {
            const float4* xr = (const float4*)(X + (size_t)grow * F);
            va = xr[2 * c];
            vb = xr[2 * c + 1];
        }
        ushort8v u;
        u[0] = f2bf(va.x); u[1] = f2bf(va.y); u[2] = f2bf(va.z); u[3] = f2bf(va.w);
        u[4] = f2bf(vb.x); u[5] = f2bf(vb.y); u[6] = f2bf(vb.z); u[7] = f2bf(vb.w);
        *(ushort8v*)&Xs[r * 128 + (((c ^ (r & 7)) << 3))] = u;
    }
    __syncthreads();

    const int wid = tid >> 6;
    const int lane = tid & 63;
    const int wr = wid >> 1;
    const int wc = wid & 1;
    const int l15 = lane & 15;
    const int l4 = lane >> 4;
    const int sw = (l15 & 7);

    f32x4 acc[2][4] = {};

#pragma unroll
    for (int kc = 0; kc < 4; ++kc) {
        const int cS = ((kc * 4 + l4) ^ sw) << 3;
        short8v a0 = *(const short8v*)&Xs[(wr * 32 + 0 * 16 + l15) * 128 + cS];
        short8v a1 = *(const short8v*)&Xs[(wr * 32 + 1 * 16 + l15) * 128 + cS];
        const bf16_t* mb = Mbf + (size_t)(wc * 64 + l15) * F + kc * 32 + 8 * l4;
        short8v b0 = *(const short8v*)(mb + 0 * 16 * F);
        short8v b1 = *(const short8v*)(mb + 1 * 16 * F);
        short8v b2 = *(const short8v*)(mb + 2 * 16 * F);
        short8v b3 = *(const short8v*)(mb + 3 * 16 * F);
        acc[0][0] = __builtin_amdgcn_mfma_f32_16x16x32_bf16(a0, b0, acc[0][0], 0, 0, 0);
        acc[0][1] = __builtin_amdgcn_mfma_f32_16x16x32_bf16(a0, b1, acc[0][1], 0, 0, 0);
        acc[0][2] = __builtin_amdgcn_mfma_f32_16x16x32_bf16(a0, b2, acc[0][2], 0, 0, 0);
        acc[0][3] = __builtin_amdgcn_mfma_f32_16x16x32_bf16(a0, b3, acc[0][3], 0, 0, 0);
        acc[1][0] = __builtin_amdgcn_mfma_f32_16x16x32_bf16(a1, b0, acc[1][0], 0, 0, 0);
        acc[1][1] = __builtin_amdgcn_mfma_f32_16x16x32_bf16(a1, b1, acc[1][1], 0, 0, 0);
        acc[1][2] = __builtin_amdgcn_mfma_f32_16x16x32_bf16(a1, b2, acc[1][2], 0, 0, 0);
        acc[1][3] = __builtin_amdgcn_mfma_f32_16x16x32_bf16(a1, b3, acc[1][3], 0, 0, 0);
    }

#pragma unroll
    for (int mt = 0; mt < 2; ++mt) {
#pragma unroll
        for (int nt = 0; nt < 4; ++nt) {
#pragma unroll
            for (int r = 0; r < 4; ++r) {
                int grow = row0 + wr * 32 + mt * 16 + l4 * 4 + r;
                if (grow < N_NODES) {
                    int gcol = wc * 64 + nt * 16 + l15;
                    G[(size_t)grow * F + gcol] = f2bf(acc[mt][nt][r]);
                }
            }
        }
    }
}

// ---------------------------------------------------------------------------
// K4: per-bin finalize + first aggregation. Derives r0/m from cnt2, histogram
// + scan -> cnt/rofs, counting sort -> ssrc, csr write, then
// a1[n] = g[n] + sum g[ssrc] reading edge list from LDS (unroll-8 MLP).
// ---------------------------------------------------------------------------
__global__ __launch_bounds__(1024)
void k_fineagg(const unsigned int* __restrict__ ebuf, const int* __restrict__ cnt2,
               const bf16_t* __restrict__ g,
               int* __restrict__ cnt, int* __restrict__ rofs,
               unsigned short* __restrict__ csr, bf16_t* __restrict__ a1) {
    __shared__ unsigned int pairs[BINCAP];
    __shared__ unsigned short ssrc[BINCAP];
    __shared__ int hcnt[256];
    __shared__ int hofs[256];
    __shared__ int cur[256];
    __shared__ int wtot[16];
    __shared__ int r0s, ms;
    const int b = blockIdx.x;
    const int t = threadIdx.x;
    const int lane = t & 63, wv = t >> 6;

    const int lim = b * NHB;
    int part = 0;
    for (int idx = t; idx < lim; idx += 1024) part += cnt2[idx];
#pragma unroll
    for (int o = 32; o; o >>= 1) part += __shfl_xor(part, o);
    if (lane == 0) wtot[wv] = part;
    int mv = 0;
    if (t < 64) {
        mv = cnt2[lim + t];
#pragma unroll
        for (int o = 32; o; o >>= 1) mv += __shfl_xor(mv, o);
    }
    __syncthreads();
    if (t == 0) {
        int r = 0;
        for (int w = 0; w < 16; ++w) r += wtot[w];
        r0s = r;
        ms = mv;
    }
    __syncthreads();
    const int r0 = r0s;
    const int m = ms;

    for (int i = t; i < m; i += 1024) pairs[i] = ebuf[r0 + i];
    if (t < 256) hcnt[t] = 0;
    __syncthreads();
    for (int i = t; i < m; i += 1024) atomicAdd(&hcnt[(pairs[i] >> 16) & 255], 1);
    __syncthreads();

    int v = 0, incl = 0;
    if (t < 256) {
        v = hcnt[t];
        incl = v;
#pragma unroll
        for (int o = 1; o < 64; o <<= 1) {
            int u = __shfl_up(incl, o);
            if (lane >= o) incl += u;
        }
        if (lane == 63) wtot[wv] = incl;
    }
    __syncthreads();
    if (t == 0) {
        int r = 0;
        for (int w = 0; w < 4; ++w) { int x = wtot[w]; wtot[w] = r; r += x; }
    }
    __syncthreads();
    if (t < 256) {
        int excl = incl - v + wtot[wv];
        hofs[t] = excl;
        cur[t] = excl;
        int node = b * 256 + t;
        if (node < N_NODES) { cnt[node] = v; rofs[node] = r0 + excl; }
        else if (node == N_NODES) rofs[node] = N_EDGES;
    }
    __syncthreads();

    for (int i = t; i < m; i += 1024) {
        unsigned int u = pairs[i];
        int d8 = (u >> 16) & 255;
        int slot = atomicAdd(&cur[d8], 1);  // LDS atomic
        ssrc[slot] = (unsigned short)(u & 0xFFFF);
    }
    __syncthreads();
    for (int i = t; i < m; i += 1024) csr[r0 + i] = ssrc[i];

    // ---- aggregation for this bin's nodes (edge list in LDS) ----
    const int lane16 = t & 15;
    const int grp = t >> 4;  // 0..63
    for (int ln = grp; ln < 256; ln += 64) {
        int node = b * 256 + ln;
        if (node >= N_NODES) continue;
        int deg = hcnt[ln];
        int rl = hofs[ln];

        ushort8v u = ((const ushort8v*)(g + (size_t)node * F))[lane16];
        float a0 = bf2f(u[0]), a1_ = bf2f(u[1]), a2 = bf2f(u[2]), a3 = bf2f(u[3]);
        float a4 = bf2f(u[4]), a5 = bf2f(u[5]), a6 = bf2f(u[6]), a7 = bf2f(u[7]);

        int i = 0;
        for (; i + 8 <= deg; i += 8) {
            ushort8v u0 = ((const ushort8v*)(g + (size_t)ssrc[rl + i + 0] * F))[lane16];
            ushort8v u1 = ((const ushort8v*)(g + (size_t)ssrc[rl + i + 1] * F))[lane16];
            ushort8v u2 = ((const ushort8v*)(g + (size_t)ssrc[rl + i + 2] * F))[lane16];
            ushort8v u3 = ((const ushort8v*)(g + (size_t)ssrc[rl + i + 3] * F))[lane16];
            ushort8v u4 = ((const ushort8v*)(g + (size_t)ssrc[rl + i + 4] * F))[lane16];
            ushort8v u5 = ((const ushort8v*)(g + (size_t)ssrc[rl + i + 5] * F))[lane16];
            ushort8v u6 = ((const ushort8v*)(g + (size_t)ssrc[rl + i + 6] * F))[lane16];
            ushort8v u7 = ((const ushort8v*)(g + (size_t)ssrc[rl + i + 7] * F))[lane16];
            a0 += bf2f(u0[0]) + bf2f(u1[0]) + bf2f(u2[0]) + bf2f(u3[0])
                + bf2f(u4[0]) + bf2f(u5[0]) + bf2f(u6[0]) + bf2f(u7[0]);
            a1_ += bf2f(u0[1]) + bf2f(u1[1]) + bf2f(u2[1]) + bf2f(u3[1])
                 + bf2f(u4[1]) + bf2f(u5[1]) + bf2f(u6[1]) + bf2f(u7[1]);
            a2 += bf2f(u0[2]) + bf2f(u1[2]) + bf2f(u2[2]) + bf2f(u3[2])
                + bf2f(u4[2]) + bf2f(u5[2]) + bf2f(u6[2]) + bf2f(u7[2]);
            a3 += bf2f(u0[3]) + bf2f(u1[3]) + bf2f(u2[3]) + bf2f(u3[3])
                + bf2f(u4[3]) + bf2f(u5[3]) + bf2f(u6[3]) + bf2f(u7[3]);
            a4 += bf2f(u0[4]) + bf2f(u1[4]) + bf2f(u2[4]) + bf2f(u3[4])
                + bf2f(u4[4]) + bf2f(u5[4]) + bf2f(u6[4]) + bf2f(u7[4]);
            a5 += bf2f(u0[5]) + bf2f(u1[5]) + bf2f(u2[5]) + bf2f(u3[5])
                + bf2f(u4[5]) + bf2f(u5[5]) + bf2f(u6[5]) + bf2f(u7[5]);
            a6 += bf2f(u0[6]) + bf2f(u1[6]) + bf2f(u2[6]) + bf2f(u3[6])
                + bf2f(u4[6]) + bf2f(u5[6]) + bf2f(u6[6]) + bf2f(u7[6]);
            a7 += bf2f(u0[7]) + bf2f(u1[7]) + bf2f(u2[7]) + bf2f(u3[7])
                + bf2f(u4[7]) + bf2f(u5[7]) + bf2f(u6[7]) + bf2f(u7[7]);
        }
        for (; i + 4 <= deg; i += 4) {
            ushort8v u0 = ((const ushort8v*)(g + (size_t)ssrc[rl + i + 0] * F))[lane16];
            ushort8v u1 = ((const ushort8v*)(g + (size_t)ssrc[rl + i + 1] * F))[lane16];
            ushort8v u2 = ((const ushort8v*)(g + (size_t)ssrc[rl + i + 2] * F))[lane16];
            ushort8v u3 = ((const ushort8v*)(g + (size_t)ssrc[rl + i + 3] * F))[lane16];
            a0 += bf2f(u0[0]) + bf2f(u1[0]) + bf2f(u2[0]) + bf2f(u3[0]);
            a1_ += bf2f(u0[1]) + bf2f(u1[1]) + bf2f(u2[1]) + bf2f(u3[1]);
            a2 += bf2f(u0[2]) + bf2f(u1[2]) + bf2f(u2[2]) + bf2f(u3[2]);
            a3 += bf2f(u0[3]) + bf2f(u1[3]) + bf2f(u2[3]) + bf2f(u3[3]);
            a4 += bf2f(u0[4]) + bf2f(u1[4]) + bf2f(u2[4]) + bf2f(u3[4]);
            a5 += bf2f(u0[5]) + bf2f(u1[5]) + bf2f(u2[5]) + bf2f(u3[5]);
            a6 += bf2f(u0[6]) + bf2f(u1[6]) + bf2f(u2[6]) + bf2f(u3[6]);
            a7 += bf2f(u0[7]) + bf2f(u1[7]) + bf2f(u2[7]) + bf2f(u3[7]);
        }
        for (; i < deg; ++i) {
            int s = ssrc[rl + i];
            ushort8v uv = ((const ushort8v*)(g + (size_t)s * F))[lane16];
            a0 += bf2f(uv[0]); a1_ += bf2f(uv[1]); a2 += bf2f(uv[2]); a3 += bf2f(uv[3]);
            a4 += bf2f(uv[4]); a5 += bf2f(uv[5]); a6 += bf2f(uv[6]); a7 += bf2f(uv[7]);
        }
        ushort8v o;
        o[0] = f2bf(a0); o[1] = f2bf(a1_); o[2] = f2bf(a2); o[3] = f2bf(a3);
        o[4] = f2bf(a4); o[5] = f2bf(a5); o[6] = f2bf(a6); o[7] = f2bf(a7);
        ((ushort8v*)(a1 + (size_t)node * F))[lane16] = o;
    }
}

// ---------------------------------------------------------------------------
// K5: out[n] = log_softmax( (S*a1)[n] + sd_n*v1 + d_n*bc ), sd inline via
// cnt gathers; unroll-8 gather MLP; softmax over the 16-lane group.
// ---------------------------------------------------------------------------
__global__ __launch_bounds__(256)
void k_agg_ep(const bf16_t* __restrict__ H, const int* __restrict__ rofs,
              const unsigned short* __restrict__ csr, const int* __restrict__ cnt,
              const float* __restrict__ v1, const float* __restrict__ bc,
              float* __restrict__ O, int n_rows) {
    int tid = threadIdx.x;
    int lane = tid & 15;
    int node = blockIdx.x * 16 + (tid >> 4);
    if (node >= n_rows) return;

    int r0 = rofs[node];
    int deg = rofs[node + 1] - r0;

    ushort8v u = ((const ushort8v*)(H + (size_t)node * F))[lane];
    float a0 = bf2f(u[0]), a1 = bf2f(u[1]), a2 = bf2f(u[2]), a3 = bf2f(u[3]);
    float a4 = bf2f(u[4]), a5 = bf2f(u[5]), a6 = bf2f(u[6]), a7 = bf2f(u[7]);

    const unsigned short* bk = csr + r0;

    int sdi = (lane == 0) ? (deg + 1) : 0;
    for (int j = lane; j < deg; j += 16) sdi += cnt[bk[j]] + 1;

    int i = 0;
    for (; i + 8 <= deg; i += 8) {
        ushort8v u0 = ((const ushort8v*)(H + (size_t)bk[i + 0] * F))[lane];
        ushort8v u1 = ((const ushort8v*)(H + (size_t)bk[i + 1] * F))[lane];
        ushort8v u2 = ((const ushort8v*)(H + (size_t)bk[i + 2] * F))[lane];
        ushort8v u3 = ((const ushort8v*)(H + (size_t)bk[i + 3] * F))[lane];
        ushort8v u4 = ((const ushort8v*)(H + (size_t)bk[i + 4] * F))[lane];
        ushort8v u5 = ((const ushort8v*)(H + (size_t)bk[i + 5] * F))[lane];
        ushort8v u6 = ((const ushort8v*)(H + (size_t)bk[i + 6] * F))[lane];
        ushort8v u7 = ((const ushort8v*)(H + (size_t)bk[i + 7] * F))[lane];
        a0 += bf2f(u0[0]) + bf2f(u1[0]) + bf2f(u2[0]) + bf2f(u3[0])
            + bf2f(u4[0]) + bf2f(u5[0]) + bf2f(u6[0]) + bf2f(u7[0]);
        a1 += bf2f(u0[1]) + bf2f(u1[1]) + bf2f(u2[1]) + bf2f(u3[1])
            + bf2f(u4[1]) + bf2f(u5[1]) + bf2f(u6[1]) + bf2f(u7[1]);
        a2 += bf2f(u0[2]) + bf2f(u1[2]) + bf2f(u2[2]) + bf2f(u3[2])
            + bf2f(u4[2]) + bf2f(u5[2]) + bf2f(u6[2]) + bf2f(u7[2]);
        a3 += bf2f(u0[3]) + bf2f(u1[3]) + bf2f(u2[3]) + bf2f(u3[3])
            + bf2f(u4[3]) + bf2f(u5[3]) + bf2f(u6[3]) + bf2f(u7[3]);
        a4 += bf2f(u0[4]) + bf2f(u1[4]) + bf2f(u2[4]) + bf2f(u3[4])
            + bf2f(u4[4]) + bf2f(u5[4]) + bf2f(u6[4]) + bf2f(u7[4]);
        a5 += bf2f(u0[5]) + bf2f(u1[5]) + bf2f(u2[5]) + bf2f(u3[5])
            + bf2f(u4[5]) + bf2f(u5[5]) + bf2f(u6[5]) + bf2f(u7[5]);
        a6 += bf2f(u0[6]) + bf2f(u1[6]) + bf2f(u2[6]) + bf2f(u3[6])
            + bf2f(u4[6]) + bf2f(u5[6]) + bf2f(u6[6]) + bf2f(u7[6]);
        a7 += bf2f(u0[7]) + bf2f(u1[7]) + bf2f(u2[7]) + bf2f(u3[7])
            + bf2f(u4[7]) + bf2f(u5[7]) + bf2f(u6[7]) + bf2f(u7[7]);
    }
    for (; i + 4 <= deg; i += 4) {
        ushort8v u0 = ((const ushort8v*)(H + (size_t)bk[i + 0] * F))[lane];
        ushort8v u1 = ((const ushort8v*)(H + (size_t)bk[i + 1] * F))[lane];
        ushort8v u2 = ((const ushort8v*)(H + (size_t)bk[i + 2] * F))[lane];
        ushort8v u3 = ((const ushort8v*)(H + (size_t)bk[i + 3] * F))[lane];
        a0 += bf2f(u0[0]) + bf2f(u1[0]) + bf2f(u2[0]) + bf2f(u3[0]);
        a1 += bf2f(u0[1]) + bf2f(u1[1]) + bf2f(u2[1]) + bf2f(u3[1]);
        a2 += bf2f(u0[2]) + bf2f(u1[2]) + bf2f(u2[2]) + bf2f(u3[2]);
        a3 += bf2f(u0[3]) + bf2f(u1[3]) + bf2f(u2[3]) + bf2f(u3[3]);
        a4 += bf2f(u0[4]) + bf2f(u1[4]) + bf2f(u2[4]) + bf2f(u3[4]);
        a5 += bf2f(u0[5]) + bf2f(u1[5]) + bf2f(u2[5]) + bf2f(u3[5]);
        a6 += bf2f(u0[6]) + bf2f(u1[6]) + bf2f(u2[6]) + bf2f(u3[6]);
        a7 += bf2f(u0[7]) + bf2f(u1[7]) + bf2f(u2[7]) + bf2f(u3[7]);
    }
    for (; i < deg; ++i) {
        ushort8v uv = ((const ushort8v*)(H + (size_t)bk[i] * F))[lane];
        a0 += bf2f(uv[0]); a1 += bf2f(uv[1]); a2 += bf2f(uv[2]); a3 += bf2f(uv[3]);
        a4 += bf2f(uv[4]); a5 += bf2f(uv[5]); a6 += bf2f(uv[6]); a7 += bf2f(uv[7]);
    }

#pragma unroll
    for (int o = 8; o; o >>= 1) sdi += __shfl_xor(sdi, o);
    float sdn = (float)sdi;
    float dn = (float)(deg + 1);
    float4 v1a = ((const float4*)v1)[2 * lane], v1b = ((const float4*)v1)[2 * lane + 1];
    float4 bca = ((const float4*)bc)[2 * lane], bcb = ((const float4*)bc)[2 * lane + 1];
    a0 += sdn * v1a.x + dn * bca.x;
    a1 += sdn * v1a.y + dn * bca.y;
    a2 += sdn * v1a.z + dn * bca.z;
    a3 += sdn * v1a.w + dn * bca.w;
    a4 += sdn * v1b.x + dn * bcb.x;
    a5 += sdn * v1b.y + dn * bcb.y;
    a6 += sdn * v1b.z + dn * bcb.z;
    a7 += sdn * v1b.w + dn * bcb.w;

    float m = fmaxf(fmaxf(fmaxf(a0, a1), fmaxf(a2, a3)),
                    fmaxf(fmaxf(a4, a5), fmaxf(a6, a7)));
#pragma unroll
    for (int o = 8; o; o >>= 1) m = fmaxf(m, __shfl_xor(m, o));
    float s = expf(a0 - m) + expf(a1 - m) + expf(a2 - m) + expf(a3 - m)
            + expf(a4 - m) + expf(a5 - m) + expf(a6 - m) + expf(a7 - m);
#pragma unroll
    for (int o = 8; o; o >>= 1) s += __shfl_xor(s, o);
    float lse = m + logf(s);
    float4 oa, ob;
    oa.x = a0 - lse; oa.y = a1 - lse; oa.z = a2 - lse; oa.w = a3 - lse;
    ob.x = a4 - lse; ob.y = a5 - lse; ob.z = a6 - lse; ob.w = a7 - lse;
    ((float4*)(O + (size_t)node * F))[2 * lane] = oa;
    ((float4*)(O + (size_t)node * F))[2 * lane + 1] = ob;
}

extern "C" void kernel_launch(void* const* d_in, const int* in_sizes, int n_in,
                              void* d_out, int out_size, void* d_ws, size_t ws_size,
                              hipStream_t stream) {
    const float* x  = (const float*)d_in[0];
    const int* ei   = (const int*)d_in[1];
    const float* w1 = (const float*)d_in[2];
    const float* b1 = (const float*)d_in[3];
    const float* w2 = (const float*)d_in[4];
    const float* b2 = (const float*)d_in[5];
    float* out = (float*)d_out;

    const int* src = ei;
    const int* dst = ei + N_EDGES;

    // workspace layout (float offsets, 16B aligned)
    float* ws        = (float*)d_ws;
    float* Wc        = ws;                          // 16384
    float* bc        = ws + 16384;                  // 128
    float* v1        = ws + 16512;                  // 128
    bf16_t* Mbf      = (bf16_t*)(ws + 16640);       // 16384 bf16 (8192 f)
    int*   cnt       = (int*)(ws + 24832);          // 50048
    int*   rofs      = (int*)(ws + 74880);          // 50001 (pad 50048)
    int*   cnt2      = (int*)(ws + 124928);         // 12544 (pad 12800)
    unsigned int* ebuf = (unsigned int*)(ws + 137728);     // 600000 u32
    unsigned short* csr = (unsigned short*)(ws + 737728);  // 600000 u16 (300000 f)
    bf16_t* g        = (bf16_t*)(ws + 1037728);     // 6.4M bf16 (3.2M f)
    bf16_t* a1       = (bf16_t*)(ws + 4237728);     // 6.4M bf16

    const int node_grid = (N_NODES + 15) / 16;  // 3125

    // K1: weight fuse (128 blocks) || coarse histogram (NHB blocks)
    k_prep<<<128 + NHB, 256, 0, stream>>>(w1, b1, w2, b2, Wc, bc, dst, cnt2);
    // K2: Mbf + v1 (parallel, 16 blocks)
    k_mbf<<<16, 1024, 0, stream>>>(Wc, bc, Mbf, v1);
    // K3: g = x*M (MFMA) || passB self-scanned LDS-sorted grouped scatter
    k_mainB<<<GEMM_BLOCKS + NHB, 256, 0, stream>>>(x, Mbf, g, src, dst, cnt2, ebuf);
    // K4: per-bin sort -> cnt/rofs/csr + first aggregation (a1 = S*g)
    k_fineagg<<<NBINS, 1024, 0, stream>>>(ebuf, cnt2, g, cnt, rofs, csr, a1);
    // K5: out = log_softmax(S*a1 + sd*v1^T + d*bc^T)
    k_agg_ep<<<node_grid, 256, 0, stream>>>(a1, rofs, csr, cnt, v1, bc, out, N_NODES);
}